// Round 8
// baseline (316.039 us; speedup 1.0000x reference)
//
#include <hip/hip_runtime.h>
#include <hip/hip_bf16.h>
#include <cstdint>

// ---------------------------------------------------------------------------
// TempoSpikeSelfAttention on MI355X (gfx950), bf16-MFMA pipeline.  v8
//   dims: T=4 B=4 N=1024 D=768 H=12 Dh=64 -> M = T*B*N = 16384 rows
// v8 changes (vs v7, 313.5 us measured; QKV GEMM 98 us / MfmaUtil 24.5%):
//   * attn32: K/V LDS fragment reads are qs-invariant but were issued inside
//     the qs loop -> every wave read all 32 fragments TWICE. Restructured:
//     mt-outer QK^T shares each kf across both qs (st0/st1 dual accum);
//     kc-outer PV shares each vb across both qs (both pf built first).
//     32 -> 16 ds_read_b128 per wave per kv-tile; math bitwise identical.
// Pipeline:
//   1. cast_all: x, Wq|Wk|Wv (concat), Wo -> bf16 (one dispatch)
//   2. QKV GEMM (3-buf counted-vmcnt): QKV[16384,2304] bf16, bias fused;
//      V column-blocks written TRANSPOSED straight to Vt[(tb*12+h)*64+d][n]
//   3. attn32: grid (192 heads, 4 qt); S^T = K Q^T (mfma 32x32x16);
//      P C-layout -> B-layout in regs via v_permlane32_swap_b32;
//      octx += V^T P; L1-normalize in regs.
//   4. O GEMM: out = CTX @ Wo^T + bo -> fp32 d_out
// ---------------------------------------------------------------------------

typedef __attribute__((ext_vector_type(8))) short short8;     // 8 bf16 = 4 VGPR
typedef __attribute__((ext_vector_type(4))) float float4v;    // 16x16 acc
typedef __attribute__((ext_vector_type(16))) float float16v;  // 32x32 acc

__device__ __forceinline__ unsigned short f2bf(float f) {
  unsigned int u = __float_as_uint(f);
  u = (u + 0x7fffu + ((u >> 16) & 1u)) >> 16;   // RNE
  return (unsigned short)u;
}

// pack two f32 -> two bf16 (round-half-away) in one v_perm_b32
__device__ __forceinline__ unsigned int pkbf(float a, float b) {
  unsigned int ua = __float_as_uint(a) + 0x8000u;
  unsigned int ub = __float_as_uint(b) + 0x8000u;
  return __builtin_amdgcn_perm(ub, ua, 0x07060302u);  // [bf(a) lo16 | bf(b) hi16]
}

// async global->LDS, 16B per lane; LDS dest = wave-uniform base + lane*16
__device__ __forceinline__ void gld_lds16(const void* g, void* lds) {
  __builtin_amdgcn_global_load_lds(
      (__attribute__((address_space(1))) void*)(uintptr_t)g,
      (__attribute__((address_space(3))) void*)(uint32_t)(uintptr_t)lds,
      16, 0, 0);
}

// ---------------------------------------------------------------------------
// One dispatch for all fp32->bf16 casts. Block-uniform routing:
//   blocks [0,12288)        : x   (3145728 float4)
//   blocks [12288,12288+576): Wq -> WQKV[0]
//   next 576                : Wk -> WQKV+589824
//   next 576                : Wv -> WQKV+1179648
//   next 576                : Wo -> WOb
__global__ __launch_bounds__(256) void cast_all(
    const float* __restrict__ x,  const float* __restrict__ Wq,
    const float* __restrict__ Wk, const float* __restrict__ Wv,
    const float* __restrict__ Wo, unsigned short* __restrict__ XBF,
    unsigned short* __restrict__ WQKV, unsigned short* __restrict__ WOb) {
  const int bid = blockIdx.x;
  const float* src;
  unsigned short* dst;
  int i;
  if (bid < 12288) {
    src = x; dst = XBF; i = bid * 256 + threadIdx.x;
  } else {
    const int wb = bid - 12288;          // 0..2303
    const int which = wb / 576;
    i = (wb % 576) * 256 + threadIdx.x;  // < 147456
    src = (which == 0) ? Wq : (which == 1) ? Wk : (which == 2) ? Wv : Wo;
    dst = (which == 0) ? WQKV
        : (which == 1) ? WQKV + 589824
        : (which == 2) ? WQKV + 1179648 : WOb;
  }
  float4 f = reinterpret_cast<const float4*>(src)[i];
  ushort4 o;
  o.x = f2bf(f.x); o.y = f2bf(f.y); o.z = f2bf(f.z); o.w = f2bf(f.w);
  reinterpret_cast<ushort4*>(dst)[i] = o;
}

// ---------------------------------------------------------------------------
// C[i,j] = sum_k A[i,k] * Bt[j,k] + bias[j].  K=768 fixed. 128x128 tile, BK=32.
// 4 waves in 2x2, each 64x64 (4x4 mfma 16x16x32 tiles).
// 3-buffer 2-deep pipeline, counted vmcnt (never 0 in steady state).
// OUT_BF16 path: column-blocks with sel==2 (V) are written TRANSPOSED to Vt.
template <bool OUT_BF16>
__global__ __launch_bounds__(256) void gemm_bt(
    const unsigned short* __restrict__ A,   // [M,768] bf16
    const unsigned short* __restrict__ Bt,  // [N,768] bf16
    unsigned short* __restrict__ Cb,        // bf16 out [M,N]
    float* __restrict__ Cf,                 // f32 out  [M,N]
    unsigned short* __restrict__ Vt,        // bf16 out [(tb*12+h)*64+d][1024]
    const float* __restrict__ b0, const float* __restrict__ b1,
    const float* __restrict__ b2, int N) {
  constexpr int K = 768;
  constexpr int KT = K / 32;                   // 24 K-tiles
  __shared__ unsigned short As[3][128 * 32];   // row stride 32 el (64 B)
  __shared__ unsigned short Bs[3][128 * 32];

  const int tid = threadIdx.x;
  const int lane = tid & 63;
  const int w = tid >> 6;
  const int wrow = w >> 1, wcol = w & 1;
  const int l15 = lane & 15, quad = lane >> 4;

  // Bijective XCD swizzle: HW linear id (x-fastest) -> logical id so that
  // 8*per consecutive logical blocks (sharing A-tiles) sit on one XCD.
  const int gx = gridDim.x;
  const int nwg = gx * gridDim.y;                   // 2304 or 768; % 8 == 0
  const int hw = blockIdx.y * gx + blockIdx.x;
  const int per = nwg >> 3;
  const int lg = (hw & 7) * per + (hw >> 3);
  const int bx = lg % gx, by = lg / gx;
  const int i0 = by * 128, j0 = bx * 128;

  const unsigned short* ga = A + (size_t)(i0 + 32 * w + (lane >> 2)) * K + (lane & 3) * 8;
  const unsigned short* gb = Bt + (size_t)(j0 + 32 * w + (lane >> 2)) * K + (lane & 3) * 8;

  // stage K-tile kt2 into LDS buffer bufi (4 gld_lds per wave)
  auto stage = [&](int kt2, int bufi) {
    const unsigned short* pa = ga + kt2 * 32;
    const unsigned short* pb = gb + kt2 * 32;
    gld_lds16(pa, &As[bufi][(32 * w) * 32]);
    gld_lds16(pa + 16 * K, &As[bufi][(32 * w + 16) * 32]);
    gld_lds16(pb, &Bs[bufi][(32 * w) * 32]);
    gld_lds16(pb + 16 * K, &Bs[bufi][(32 * w + 16) * 32]);
  };

  float4v acc[4][4];
#pragma unroll
  for (int a = 0; a < 4; ++a)
#pragma unroll
    for (int b = 0; b < 4; ++b) acc[a][b] = float4v{0.f, 0.f, 0.f, 0.f};

  // prologue: 2 tiles in flight; wait for tile 0 only (vmcnt(4))
  stage(0, 0);
  stage(1, 1);
  asm volatile("s_waitcnt vmcnt(4)" ::: "memory");
  __builtin_amdgcn_s_barrier();
  __builtin_amdgcn_sched_barrier(0);

#pragma unroll 1
  for (int kt = 0; kt < KT; ++kt) {
    const int cur = kt % 3;
    if (kt + 2 < KT) stage(kt + 2, (kt + 2) % 3);  // 2-deep prefetch

    short8 af[4], bfr[4];
#pragma unroll
    for (int a = 0; a < 4; ++a)
      af[a] = *(const short8*)&As[cur][(wrow * 64 + a * 16 + l15) * 32 + quad * 8];
#pragma unroll
    for (int b = 0; b < 4; ++b)
      bfr[b] = *(const short8*)&Bs[cur][(wcol * 64 + b * 16 + l15) * 32 + quad * 8];
#pragma unroll
    for (int a = 0; a < 4; ++a)
#pragma unroll
      for (int b = 0; b < 4; ++b)
        acc[a][b] = __builtin_amdgcn_mfma_f32_16x16x32_bf16(af[a], bfr[b], acc[a][b], 0, 0, 0);

    // gate tile kt+1 residency; keep tile kt+2's 4 loads in flight
    if (kt + 2 < KT) {
      asm volatile("s_waitcnt vmcnt(4)" ::: "memory");
      __builtin_amdgcn_s_barrier();
      __builtin_amdgcn_sched_barrier(0);
    } else if (kt + 1 < KT) {
      asm volatile("s_waitcnt vmcnt(0)" ::: "memory");
      __builtin_amdgcn_s_barrier();
      __builtin_amdgcn_sched_barrier(0);
    }
    // last iter: no barrier; epilogue touches no LDS
  }

  const int sel = j0 / 768;
  const float* bp = (sel == 0) ? b0 : ((sel == 1) ? b1 : b2);
#pragma unroll
  for (int a = 0; a < 4; ++a) {
    const int row0 = i0 + wrow * 64 + a * 16 + quad * 4;
#pragma unroll
    for (int b = 0; b < 4; ++b) {
      const int col = j0 + wcol * 64 + b * 16 + l15;
      const float bias = bp[col - sel * 768];
      if (OUT_BF16 && sel == 2) {
        // V block -> transposed store into Vt.
        const int tb = row0 >> 10;
        const int n0 = row0 & 1023;            // multiple of 4 -> 8B aligned
        const int hd = col - 1536;             // h*64 + d
        const float v0 = acc[a][b][0] + bias;
        const float v1 = acc[a][b][1] + bias;
        const float v2 = acc[a][b][2] + bias;
        const float v3 = acc[a][b][3] + bias;
        uint2 u;
        u.x = (unsigned int)f2bf(v0) | ((unsigned int)f2bf(v1) << 16);
        u.y = (unsigned int)f2bf(v2) | ((unsigned int)f2bf(v3) << 16);
        *(uint2*)&Vt[((size_t)(tb * 768 + hd)) * 1024 + n0] = u;
      } else {
#pragma unroll
        for (int r = 0; r < 4; ++r) {
          const float v = acc[a][b][r] + bias;
          if (OUT_BF16)
            Cb[(size_t)(row0 + r) * N + col] = f2bf(v);
          else
            Cf[(size_t)(row0 + r) * N + col] = v;
        }
      }
    }
  }
}

// ---------------------------------------------------------------------------
// Attention v8. Grid (tbh=192, qt=4); 256 thr = 4 waves; wave = 64 q (2 x 32).
// Per kv-tile: K/V fragments are qs-invariant -> read each ONCE:
//   QK^T mt-outer: kf shared across qs (st0/st1 dual accumulators)
//   PV   kc-outer: vb shared across qs (both pf built before the dt loop)
// 16 ds_read_b128 per wave per kv-tile (was 32). Math bitwise identical.
__global__ __launch_bounds__(256) void attn32(
    const unsigned short* __restrict__ qkv,  // [16384, 2304] bf16
    const unsigned short* __restrict__ vt,   // [(tbh)*64 + d][1024] bf16
    unsigned short* __restrict__ ctx) {      // [16384, 768] bf16
  __shared__ unsigned short Ks[64 * 72];     // [kv_local][d], padded
  __shared__ unsigned short Vs[64 * 72];     // [d][kv_local], padded

  const int tbh = blockIdx.x;                // same-head blocks: ids 192 apart
  const int qt = blockIdx.y;                 // -> same XCD (192 % 8 == 0)
  const int tb = tbh / 12, h = tbh % 12;
  const int tid = threadIdx.x, lane = tid & 63, w = tid >> 6;
  const int l31 = lane & 31, hl = lane >> 5;

  // ---- Q fragments: one-time scattered global loads ----
  short8 qf[2][4];   // [qs][kc]: B-op: lane holds Q[q=.. +l31][kc*16+hl*8+j]
#pragma unroll
  for (int qs = 0; qs < 2; ++qs) {
    const unsigned short* qp =
        qkv + (size_t)(tb * 1024 + qt * 256 + w * 64 + qs * 32 + l31) * 2304 +
        h * 64 + hl * 8;
#pragma unroll
    for (int kc = 0; kc < 4; ++kc) qf[qs][kc] = *(const short8*)(qp + kc * 16);
  }

  // ---- staging: 256 thr cover 64 rows x 8 chunks of 16B, 2 rows/thread ----
  const int srow = tid >> 3;   // 0..31 (and +32)
  const int sblk = tid & 7;
  const unsigned short* kcol =
      qkv + (size_t)(tb * 1024) * 2304 + 768 + h * 64 + sblk * 8;
  const unsigned short* vcol = vt + ((size_t)tbh * 64 + srow) * 1024 + sblk * 8;
  uint4 kr0, kr1, vr0, vr1;
  auto loadKV = [&](int kv) {
    const unsigned short* kp = kcol + (size_t)(kv * 64 + srow) * 2304;
    kr0 = *(const uint4*)kp;
    kr1 = *(const uint4*)(kp + 32 * 2304);
    const unsigned short* vp = vcol + kv * 64;
    vr0 = *(const uint4*)vp;
    vr1 = *(const uint4*)(vp + 32 * 1024);
  };

  float16v octx[2][2];   // [qs][dt]; C: row=d_local, col=q=l31
#pragma unroll
  for (int qs = 0; qs < 2; ++qs)
#pragma unroll
    for (int dt = 0; dt < 2; ++dt)
#pragma unroll
      for (int i = 0; i < 16; ++i) octx[qs][dt][i] = 0.f;
  float den[2] = {0.f, 0.f};

  loadKV(0);

#pragma unroll 1
  for (int kv = 0; kv < 16; ++kv) {
    __syncthreads();   // #1: all reads of tile kv-1 done; drains loads of kv
    *(uint4*)&Ks[srow * 72 + sblk * 8] = kr0;
    *(uint4*)&Ks[(srow + 32) * 72 + sblk * 8] = kr1;
    *(uint4*)&Vs[srow * 72 + sblk * 8] = vr0;
    *(uint4*)&Vs[(srow + 32) * 72 + sblk * 8] = vr1;
    __syncthreads();   // #2: writes visible (vmcnt trivially 0 here)
    if (kv < 15) loadKV(kv + 1);   // in flight across compute below

    // ---- QK^T, mt-outer; kf read once, used by both qs ----
    unsigned int pk[2][2][8];   // [qs][mt][g*2+p]
#pragma unroll
    for (int mt = 0; mt < 2; ++mt) {
      float16v st0, st1;
#pragma unroll
      for (int i = 0; i < 16; ++i) { st0[i] = 0.f; st1[i] = 0.f; }
#pragma unroll
      for (int kc = 0; kc < 4; ++kc) {
        short8 kf =
            *(const short8*)&Ks[(mt * 32 + l31) * 72 + kc * 16 + hl * 8];
        st0 = __builtin_amdgcn_mfma_f32_32x32x16_bf16(kf, qf[0][kc], st0, 0, 0, 0);
        st1 = __builtin_amdgcn_mfma_f32_32x32x16_bf16(kf, qf[1][kc], st1, 0, 0, 0);
      }
#pragma unroll
      for (int g = 0; g < 4; ++g) {
        {  // qs = 0
          float v0 = st0[4 * g + 0]; v0 = v0 > 0.f ? v0 : 0.f;
          float v1 = st0[4 * g + 1]; v1 = v1 > 0.f ? v1 : 0.f;
          float v2 = st0[4 * g + 2]; v2 = v2 > 0.f ? v2 : 0.f;
          float v3 = st0[4 * g + 3]; v3 = v3 > 0.f ? v3 : 0.f;
          den[0] += (v0 + v1) + (v2 + v3);
          pk[0][mt][g * 2 + 0] = pkbf(v0, v1);
          pk[0][mt][g * 2 + 1] = pkbf(v2, v3);
        }
        {  // qs = 1
          float v0 = st1[4 * g + 0]; v0 = v0 > 0.f ? v0 : 0.f;
          float v1 = st1[4 * g + 1]; v1 = v1 > 0.f ? v1 : 0.f;
          float v2 = st1[4 * g + 2]; v2 = v2 > 0.f ? v2 : 0.f;
          float v3 = st1[4 * g + 3]; v3 = v3 > 0.f ? v3 : 0.f;
          den[1] += (v0 + v1) + (v2 + v3);
          pk[1][mt][g * 2 + 0] = pkbf(v0, v1);
          pk[1][mt][g * 2 + 1] = pkbf(v2, v3);
        }
      }
    }

    // ---- PV, kc-outer; vb read once, used by both qs ----
#pragma unroll
    for (int kc = 0; kc < 4; ++kc) {
      const int mt = kc >> 1, gb = (kc & 1) * 2;
      short8 pfs[2];
#pragma unroll
      for (int qs = 0; qs < 2; ++qs) {
        unsigned int a0 = pk[qs][mt][gb * 2 + 0], b0 = pk[qs][mt][gb * 2 + 2];
        unsigned int a1 = pk[qs][mt][gb * 2 + 1], b1 = pk[qs][mt][gb * 2 + 3];
        asm("v_permlane32_swap_b32 %0, %1" : "+v"(a0), "+v"(b0));
        asm("v_permlane32_swap_b32 %0, %1" : "+v"(a1), "+v"(b1));
        union { unsigned int u[4]; short8 s; } pf;
        pf.u[0] = a0; pf.u[1] = a1; pf.u[2] = b0; pf.u[3] = b1;
        pfs[qs] = pf.s;
      }
#pragma unroll
      for (int dt = 0; dt < 2; ++dt) {
        short8 vb =
            *(const short8*)&Vs[(dt * 32 + l31) * 72 + kc * 16 + hl * 8];
        octx[0][dt] = __builtin_amdgcn_mfma_f32_32x32x16_bf16(
            vb, pfs[0], octx[0][dt], 0, 0, 0);
        octx[1][dt] = __builtin_amdgcn_mfma_f32_32x32x16_bf16(
            vb, pfs[1], octx[1][dt], 0, 0, 0);
      }
    }
  }

  // ---- normalize + store; lane l31 owns q, all in registers ----
#pragma unroll
  for (int qs = 0; qs < 2; ++qs) {
    float d = den[qs] + __shfl_xor(den[qs], 32);
    const float sc = 1.f / (d + 8e-6f);   // folded 1/sqrt(64) scaling
    const size_t qrow = (size_t)(tb * 1024 + qt * 256 + w * 64 + qs * 32 + l31);
#pragma unroll
    for (int dt = 0; dt < 2; ++dt)
#pragma unroll
      for (int g = 0; g < 4; ++g) {
        const float v0 = octx[qs][dt][4 * g + 0] * sc;
        const float v1 = octx[qs][dt][4 * g + 1] * sc;
        const float v2 = octx[qs][dt][4 * g + 2] * sc;
        const float v3 = octx[qs][dt][4 * g + 3] * sc;
        uint2 u;
        u.x = pkbf(v0, v1);
        u.y = pkbf(v2, v3);
        *(uint2*)&ctx[qrow * 768 + h * 64 + dt * 32 + g * 8 + hl * 4] = u;
      }
  }
}

// ---------------------------------------------------------------------------
extern "C" void kernel_launch(void* const* d_in, const int* in_sizes, int n_in,
                              void* d_out, int out_size, void* d_ws, size_t ws_size,
                              hipStream_t stream) {
  const float* x  = (const float*)d_in[0];
  const float* Wq = (const float*)d_in[1];
  const float* bq = (const float*)d_in[2];
  const float* Wk = (const float*)d_in[3];
  const float* bk = (const float*)d_in[4];
  const float* Wv = (const float*)d_in[5];
  const float* bv = (const float*)d_in[6];
  const float* Wo = (const float*)d_in[7];
  const float* bo = (const float*)d_in[8];
  float* out = (float*)d_out;

  char* ws = (char*)d_ws;
  // workspace layout (bytes); CTX aliases XBF (XBF dead after QKV GEMM)
  unsigned short* XBF  = (unsigned short*)(ws);                  // 25165824 B
  unsigned short* CTX  = (unsigned short*)(ws);                  // alias
  unsigned short* WQKV = (unsigned short*)(ws + 25165824);       //  3538944 B
  unsigned short* WOb  = (unsigned short*)(ws + 28704768);       //  1179648 B
  unsigned short* QKV  = (unsigned short*)(ws + 29884416);       // 75497472 B
  unsigned short* VT   = (unsigned short*)(ws + 105381888);      // 25165824 B
  // total: 130547712 B

  cast_all<<<14592, 256, 0, stream>>>(x, Wq, Wk, Wv, Wo, XBF, WQKV, WOb);

  gemm_bt<true><<<dim3(18, 128), 256, 0, stream>>>(XBF, WQKV, QKV, nullptr, VT,
                                                   bq, bk, bv, 2304);
  attn32<<<dim3(192, 4), 256, 0, stream>>>(QKV, VT, CTX);
  gemm_bt<false><<<dim3(6, 128), 256, 0, stream>>>(CTX, WOb, nullptr, out,
                                                   nullptr, bo, bo, bo, 768);
}

// Round 11
// 303.099 us; speedup vs baseline: 1.0427x; 1.0427x over previous
//
#include <hip/hip_runtime.h>
#include <hip/hip_bf16.h>
#include <cstdint>

// ---------------------------------------------------------------------------
// TempoSpikeSelfAttention on MI355X (gfx950), bf16-MFMA pipeline.  v9
//   dims: T=4 B=4 N=1024 D=768 H=12 Dh=64 -> M = T*B*N = 16384 rows
// v9 changes (vs v8, 316.0 us measured; attn32 106.7 us, MfmaUtil 19%):
//   * attn32: REVERT v8's qs-invariant-read restructure (it regressed:
//     attn <98 us in r7 -> 106.7 us in r8; attn is NOT LDS-read-bound,
//     bank conflicts = 0).
//   * attn32: double-buffered K/V LDS + ONE lgkm-only barrier per kv-tile
//     (was 2 full __syncthreads, each draining vmcnt(0)+lgkmcnt(0)):
//     ds_write buf[kv&1] -> issue loads kv+1 -> s_waitcnt lgkmcnt(0) ->
//     raw s_barrier -> sched_barrier(0) -> compute buf[kv&1].
//     WAR safe: buf[cur] next overwritten at kv+2, behind barrier(kv+1),
//     and lgkmcnt(0) there drains compute(kv)'s ds_reads first.
// Pipeline:
//   1. cast_all: x, Wq|Wk|Wv (concat), Wo -> bf16 (one dispatch)
//   2. QKV GEMM (3-buf counted-vmcnt): QKV[16384,2304] bf16, bias fused;
//      V column-blocks written TRANSPOSED straight to Vt[(tb*12+h)*64+d][n]
//   3. attn32: grid (192 heads, 4 qt); S^T = K Q^T (mfma 32x32x16);
//      P C-layout -> B-layout in regs via v_permlane32_swap_b32;
//      octx += V^T P; L1-normalize in regs.
//   4. O GEMM: out = CTX @ Wo^T + bo -> fp32 d_out
// ---------------------------------------------------------------------------

typedef __attribute__((ext_vector_type(8))) short short8;     // 8 bf16 = 4 VGPR
typedef __attribute__((ext_vector_type(4))) float float4v;    // 16x16 acc
typedef __attribute__((ext_vector_type(16))) float float16v;  // 32x32 acc

__device__ __forceinline__ unsigned short f2bf(float f) {
  unsigned int u = __float_as_uint(f);
  u = (u + 0x7fffu + ((u >> 16) & 1u)) >> 16;   // RNE
  return (unsigned short)u;
}

// pack two f32 -> two bf16 (round-half-away) in one v_perm_b32
__device__ __forceinline__ unsigned int pkbf(float a, float b) {
  unsigned int ua = __float_as_uint(a) + 0x8000u;
  unsigned int ub = __float_as_uint(b) + 0x8000u;
  return __builtin_amdgcn_perm(ub, ua, 0x07060302u);  // [bf(a) lo16 | bf(b) hi16]
}

// async global->LDS, 16B per lane; LDS dest = wave-uniform base + lane*16
__device__ __forceinline__ void gld_lds16(const void* g, void* lds) {
  __builtin_amdgcn_global_load_lds(
      (__attribute__((address_space(1))) void*)(uintptr_t)g,
      (__attribute__((address_space(3))) void*)(uint32_t)(uintptr_t)lds,
      16, 0, 0);
}

// ---------------------------------------------------------------------------
// One dispatch for all fp32->bf16 casts. Block-uniform routing:
//   blocks [0,12288)        : x   (3145728 float4)
//   blocks [12288,12288+576): Wq -> WQKV[0]
//   next 576                : Wk -> WQKV+589824
//   next 576                : Wv -> WQKV+1179648
//   next 576                : Wo -> WOb
__global__ __launch_bounds__(256) void cast_all(
    const float* __restrict__ x,  const float* __restrict__ Wq,
    const float* __restrict__ Wk, const float* __restrict__ Wv,
    const float* __restrict__ Wo, unsigned short* __restrict__ XBF,
    unsigned short* __restrict__ WQKV, unsigned short* __restrict__ WOb) {
  const int bid = blockIdx.x;
  const float* src;
  unsigned short* dst;
  int i;
  if (bid < 12288) {
    src = x; dst = XBF; i = bid * 256 + threadIdx.x;
  } else {
    const int wb = bid - 12288;          // 0..2303
    const int which = wb / 576;
    i = (wb % 576) * 256 + threadIdx.x;  // < 147456
    src = (which == 0) ? Wq : (which == 1) ? Wk : (which == 2) ? Wv : Wo;
    dst = (which == 0) ? WQKV
        : (which == 1) ? WQKV + 589824
        : (which == 2) ? WQKV + 1179648 : WOb;
  }
  float4 f = reinterpret_cast<const float4*>(src)[i];
  ushort4 o;
  o.x = f2bf(f.x); o.y = f2bf(f.y); o.z = f2bf(f.z); o.w = f2bf(f.w);
  reinterpret_cast<ushort4*>(dst)[i] = o;
}

// ---------------------------------------------------------------------------
// C[i,j] = sum_k A[i,k] * Bt[j,k] + bias[j].  K=768 fixed. 128x128 tile, BK=32.
// 4 waves in 2x2, each 64x64 (4x4 mfma 16x16x32 tiles).
// 3-buffer 2-deep pipeline, counted vmcnt (never 0 in steady state).
// OUT_BF16 path: column-blocks with sel==2 (V) are written TRANSPOSED to Vt.
template <bool OUT_BF16>
__global__ __launch_bounds__(256) void gemm_bt(
    const unsigned short* __restrict__ A,   // [M,768] bf16
    const unsigned short* __restrict__ Bt,  // [N,768] bf16
    unsigned short* __restrict__ Cb,        // bf16 out [M,N]
    float* __restrict__ Cf,                 // f32 out  [M,N]
    unsigned short* __restrict__ Vt,        // bf16 out [(tb*12+h)*64+d][1024]
    const float* __restrict__ b0, const float* __restrict__ b1,
    const float* __restrict__ b2, int N) {
  constexpr int K = 768;
  constexpr int KT = K / 32;                   // 24 K-tiles
  __shared__ unsigned short As[3][128 * 32];   // row stride 32 el (64 B)
  __shared__ unsigned short Bs[3][128 * 32];

  const int tid = threadIdx.x;
  const int lane = tid & 63;
  const int w = tid >> 6;
  const int wrow = w >> 1, wcol = w & 1;
  const int l15 = lane & 15, quad = lane >> 4;

  // Bijective XCD swizzle: HW linear id (x-fastest) -> logical id so that
  // 8*per consecutive logical blocks (sharing A-tiles) sit on one XCD.
  const int gx = gridDim.x;
  const int nwg = gx * gridDim.y;                   // 2304 or 768; % 8 == 0
  const int hw = blockIdx.y * gx + blockIdx.x;
  const int per = nwg >> 3;
  const int lg = (hw & 7) * per + (hw >> 3);
  const int bx = lg % gx, by = lg / gx;
  const int i0 = by * 128, j0 = bx * 128;

  const unsigned short* ga = A + (size_t)(i0 + 32 * w + (lane >> 2)) * K + (lane & 3) * 8;
  const unsigned short* gb = Bt + (size_t)(j0 + 32 * w + (lane >> 2)) * K + (lane & 3) * 8;

  // stage K-tile kt2 into LDS buffer bufi (4 gld_lds per wave)
  auto stage = [&](int kt2, int bufi) {
    const unsigned short* pa = ga + kt2 * 32;
    const unsigned short* pb = gb + kt2 * 32;
    gld_lds16(pa, &As[bufi][(32 * w) * 32]);
    gld_lds16(pa + 16 * K, &As[bufi][(32 * w + 16) * 32]);
    gld_lds16(pb, &Bs[bufi][(32 * w) * 32]);
    gld_lds16(pb + 16 * K, &Bs[bufi][(32 * w + 16) * 32]);
  };

  float4v acc[4][4];
#pragma unroll
  for (int a = 0; a < 4; ++a)
#pragma unroll
    for (int b = 0; b < 4; ++b) acc[a][b] = float4v{0.f, 0.f, 0.f, 0.f};

  // prologue: 2 tiles in flight; wait for tile 0 only (vmcnt(4))
  stage(0, 0);
  stage(1, 1);
  asm volatile("s_waitcnt vmcnt(4)" ::: "memory");
  __builtin_amdgcn_s_barrier();
  __builtin_amdgcn_sched_barrier(0);

#pragma unroll 1
  for (int kt = 0; kt < KT; ++kt) {
    const int cur = kt % 3;
    if (kt + 2 < KT) stage(kt + 2, (kt + 2) % 3);  // 2-deep prefetch

    short8 af[4], bfr[4];
#pragma unroll
    for (int a = 0; a < 4; ++a)
      af[a] = *(const short8*)&As[cur][(wrow * 64 + a * 16 + l15) * 32 + quad * 8];
#pragma unroll
    for (int b = 0; b < 4; ++b)
      bfr[b] = *(const short8*)&Bs[cur][(wcol * 64 + b * 16 + l15) * 32 + quad * 8];
#pragma unroll
    for (int a = 0; a < 4; ++a)
#pragma unroll
      for (int b = 0; b < 4; ++b)
        acc[a][b] = __builtin_amdgcn_mfma_f32_16x16x32_bf16(af[a], bfr[b], acc[a][b], 0, 0, 0);

    // gate tile kt+1 residency; keep tile kt+2's 4 loads in flight
    if (kt + 2 < KT) {
      asm volatile("s_waitcnt vmcnt(4)" ::: "memory");
      __builtin_amdgcn_s_barrier();
      __builtin_amdgcn_sched_barrier(0);
    } else if (kt + 1 < KT) {
      asm volatile("s_waitcnt vmcnt(0)" ::: "memory");
      __builtin_amdgcn_s_barrier();
      __builtin_amdgcn_sched_barrier(0);
    }
    // last iter: no barrier; epilogue touches no LDS
  }

  const int sel = j0 / 768;
  const float* bp = (sel == 0) ? b0 : ((sel == 1) ? b1 : b2);
#pragma unroll
  for (int a = 0; a < 4; ++a) {
    const int row0 = i0 + wrow * 64 + a * 16 + quad * 4;
#pragma unroll
    for (int b = 0; b < 4; ++b) {
      const int col = j0 + wcol * 64 + b * 16 + l15;
      const float bias = bp[col - sel * 768];
      if (OUT_BF16 && sel == 2) {
        // V block -> transposed store into Vt.
        const int tb = row0 >> 10;
        const int n0 = row0 & 1023;            // multiple of 4 -> 8B aligned
        const int hd = col - 1536;             // h*64 + d
        const float v0 = acc[a][b][0] + bias;
        const float v1 = acc[a][b][1] + bias;
        const float v2 = acc[a][b][2] + bias;
        const float v3 = acc[a][b][3] + bias;
        uint2 u;
        u.x = (unsigned int)f2bf(v0) | ((unsigned int)f2bf(v1) << 16);
        u.y = (unsigned int)f2bf(v2) | ((unsigned int)f2bf(v3) << 16);
        *(uint2*)&Vt[((size_t)(tb * 768 + hd)) * 1024 + n0] = u;
      } else {
#pragma unroll
        for (int r = 0; r < 4; ++r) {
          const float v = acc[a][b][r] + bias;
          if (OUT_BF16)
            Cb[(size_t)(row0 + r) * N + col] = f2bf(v);
          else
            Cf[(size_t)(row0 + r) * N + col] = v;
        }
      }
    }
  }
}

// ---------------------------------------------------------------------------
// Attention v9. Grid (tbh=192, qt=4); 256 thr = 4 waves; wave = 64 q (2 x 32).
// Double-buffered K/V LDS, ONE lgkm-only barrier per kv-tile:
//   ds_write buf[kv&1] (reg deps auto-wait the global loads) ->
//   issue loads kv+1 (stay in flight across the barrier) ->
//   s_waitcnt lgkmcnt(0) -> s_barrier -> sched_barrier(0) -> compute.
// Compute body = r7's verified qs-outer structure (v8 revert).
__global__ __launch_bounds__(256) void attn32(
    const unsigned short* __restrict__ qkv,  // [16384, 2304] bf16
    const unsigned short* __restrict__ vt,   // [(tbh)*64 + d][1024] bf16
    unsigned short* __restrict__ ctx) {      // [16384, 768] bf16
  __shared__ unsigned short Ks[2][64 * 72];  // [buf][kv_local][d], padded
  __shared__ unsigned short Vs[2][64 * 72];  // [buf][d][kv_local], padded

  const int tbh = blockIdx.x;                // same-head blocks: ids 192 apart
  const int qt = blockIdx.y;                 // -> same XCD (192 % 8 == 0)
  const int tb = tbh / 12, h = tbh % 12;
  const int tid = threadIdx.x, lane = tid & 63, w = tid >> 6;
  const int l31 = lane & 31, hl = lane >> 5;

  // ---- Q fragments: one-time scattered global loads ----
  short8 qf[2][4];   // [qs][kc]: B-op: lane holds Q[q=.. +l31][kc*16+hl*8+j]
#pragma unroll
  for (int qs = 0; qs < 2; ++qs) {
    const unsigned short* qp =
        qkv + (size_t)(tb * 1024 + qt * 256 + w * 64 + qs * 32 + l31) * 2304 +
        h * 64 + hl * 8;
#pragma unroll
    for (int kc = 0; kc < 4; ++kc) qf[qs][kc] = *(const short8*)(qp + kc * 16);
  }

  // ---- staging: 256 thr cover 64 rows x 8 chunks of 16B, 2 rows/thread ----
  const int srow = tid >> 3;   // 0..31 (and +32)
  const int sblk = tid & 7;
  const unsigned short* kcol =
      qkv + (size_t)(tb * 1024) * 2304 + 768 + h * 64 + sblk * 8;
  const unsigned short* vcol = vt + ((size_t)tbh * 64 + srow) * 1024 + sblk * 8;
  uint4 kr0, kr1, vr0, vr1;
  auto loadKV = [&](int kv) {
    const unsigned short* kp = kcol + (size_t)(kv * 64 + srow) * 2304;
    kr0 = *(const uint4*)kp;
    kr1 = *(const uint4*)(kp + 32 * 2304);
    const unsigned short* vp = vcol + kv * 64;
    vr0 = *(const uint4*)vp;
    vr1 = *(const uint4*)(vp + 32 * 1024);
  };

  float16v octx[2][2];   // [qs][dt]; C: row=d_local, col=q=l31
#pragma unroll
  for (int qs = 0; qs < 2; ++qs)
#pragma unroll
    for (int dt = 0; dt < 2; ++dt)
#pragma unroll
      for (int i = 0; i < 16; ++i) octx[qs][dt][i] = 0.f;
  float den[2] = {0.f, 0.f};

  loadKV(0);

#pragma unroll 1
  for (int kv = 0; kv < 16; ++kv) {
    const int cur = kv & 1;
    // stage tile kv into buf[cur]; reg deps make HW wait on kv's loads only
    *(uint4*)&Ks[cur][srow * 72 + sblk * 8] = kr0;
    *(uint4*)&Ks[cur][(srow + 32) * 72 + sblk * 8] = kr1;
    *(uint4*)&Vs[cur][srow * 72 + sblk * 8] = vr0;
    *(uint4*)&Vs[cur][(srow + 32) * 72 + sblk * 8] = vr1;
    if (kv < 15) loadKV(kv + 1);   // in flight across barrier + compute
    asm volatile("s_waitcnt lgkmcnt(0)" ::: "memory");  // my ds_writes done
    __builtin_amdgcn_s_barrier();                       // no vmcnt drain
    __builtin_amdgcn_sched_barrier(0);

#pragma unroll
    for (int qs = 0; qs < 2; ++qs) {
      // S^T = K.Q^T, then relu+den+pack (C: col=q=l31, row=kv=4hl+(r)+8g+32mt)
      unsigned int pk[2][8];   // [mt][g*2+p]
#pragma unroll
      for (int mt = 0; mt < 2; ++mt) {
        float16v st;
#pragma unroll
        for (int i = 0; i < 16; ++i) st[i] = 0.f;
#pragma unroll
        for (int kc = 0; kc < 4; ++kc) {
          short8 kf =
              *(const short8*)&Ks[cur][(mt * 32 + l31) * 72 + kc * 16 + hl * 8];
          st = __builtin_amdgcn_mfma_f32_32x32x16_bf16(kf, qf[qs][kc], st, 0, 0, 0);
        }
#pragma unroll
        for (int g = 0; g < 4; ++g) {
          float v0 = st[4 * g + 0]; v0 = v0 > 0.f ? v0 : 0.f;
          float v1 = st[4 * g + 1]; v1 = v1 > 0.f ? v1 : 0.f;
          float v2 = st[4 * g + 2]; v2 = v2 > 0.f ? v2 : 0.f;
          float v3 = st[4 * g + 3]; v3 = v3 > 0.f ? v3 : 0.f;
          den[qs] += (v0 + v1) + (v2 + v3);
          pk[mt][g * 2 + 0] = pkbf(v0, v1);
          pk[mt][g * 2 + 1] = pkbf(v2, v3);
        }
      }
      // C-layout -> PV B-operand layout entirely in registers.
#pragma unroll
      for (int kc = 0; kc < 4; ++kc) {
        const int mt = kc >> 1, gb = (kc & 1) * 2;
        unsigned int a0 = pk[mt][gb * 2 + 0], b0 = pk[mt][gb * 2 + 2];
        unsigned int a1 = pk[mt][gb * 2 + 1], b1 = pk[mt][gb * 2 + 3];
        asm("v_permlane32_swap_b32 %0, %1" : "+v"(a0), "+v"(b0));
        asm("v_permlane32_swap_b32 %0, %1" : "+v"(a1), "+v"(b1));
        union { unsigned int u[4]; short8 s; } pf;
        pf.u[0] = a0; pf.u[1] = a1; pf.u[2] = b0; pf.u[3] = b1;
#pragma unroll
        for (int dt = 0; dt < 2; ++dt) {
          short8 vb =
              *(const short8*)&Vs[cur][(dt * 32 + l31) * 72 + kc * 16 + hl * 8];
          octx[qs][dt] = __builtin_amdgcn_mfma_f32_32x32x16_bf16(
              vb, pf.s, octx[qs][dt], 0, 0, 0);
        }
      }
    }
    // no trailing barrier: buf[cur] next overwritten at kv+2, behind the
    // barrier of kv+1 whose lgkmcnt(0) drains this iter's ds_reads.
  }

  // ---- normalize + store; lane l31 owns q, all in registers ----
#pragma unroll
  for (int qs = 0; qs < 2; ++qs) {
    float d = den[qs] + __shfl_xor(den[qs], 32);
    const float sc = 1.f / (d + 8e-6f);   // folded 1/sqrt(64) scaling
    const size_t qrow = (size_t)(tb * 1024 + qt * 256 + w * 64 + qs * 32 + l31);
#pragma unroll
    for (int dt = 0; dt < 2; ++dt)
#pragma unroll
      for (int g = 0; g < 4; ++g) {
        const float v0 = octx[qs][dt][4 * g + 0] * sc;
        const float v1 = octx[qs][dt][4 * g + 1] * sc;
        const float v2 = octx[qs][dt][4 * g + 2] * sc;
        const float v3 = octx[qs][dt][4 * g + 3] * sc;
        uint2 u;
        u.x = pkbf(v0, v1);
        u.y = pkbf(v2, v3);
        *(uint2*)&ctx[qrow * 768 + h * 64 + dt * 32 + g * 8 + hl * 4] = u;
      }
  }
}

// ---------------------------------------------------------------------------
extern "C" void kernel_launch(void* const* d_in, const int* in_sizes, int n_in,
                              void* d_out, int out_size, void* d_ws, size_t ws_size,
                              hipStream_t stream) {
  const float* x  = (const float*)d_in[0];
  const float* Wq = (const float*)d_in[1];
  const float* bq = (const float*)d_in[2];
  const float* Wk = (const float*)d_in[3];
  const float* bk = (const float*)d_in[4];
  const float* Wv = (const float*)d_in[5];
  const float* bv = (const float*)d_in[6];
  const float* Wo = (const float*)d_in[7];
  const float* bo = (const float*)d_in[8];
  float* out = (float*)d_out;

  char* ws = (char*)d_ws;
  // workspace layout (bytes); CTX aliases XBF (XBF dead after QKV GEMM)
  unsigned short* XBF  = (unsigned short*)(ws);                  // 25165824 B
  unsigned short* CTX  = (unsigned short*)(ws);                  // alias
  unsigned short* WQKV = (unsigned short*)(ws + 25165824);       //  3538944 B
  unsigned short* WOb  = (unsigned short*)(ws + 28704768);       //  1179648 B
  unsigned short* QKV  = (unsigned short*)(ws + 29884416);       // 75497472 B
  unsigned short* VT   = (unsigned short*)(ws + 105381888);      // 25165824 B
  // total: 130547712 B

  cast_all<<<14592, 256, 0, stream>>>(x, Wq, Wk, Wv, Wo, XBF, WQKV, WOb);

  gemm_bt<true><<<dim3(18, 128), 256, 0, stream>>>(XBF, WQKV, QKV, nullptr, VT,
                                                   bq, bk, bv, 2304);
  attn32<<<dim3(192, 4), 256, 0, stream>>>(QKV, VT, CTX);
  gemm_bt<false><<<dim3(6, 128), 256, 0, stream>>>(CTX, WOb, nullptr, out,
                                                   nullptr, bo, bo, bo, 768);
}